// Round 1
// baseline (239.073 us; speedup 1.0000x reference)
//
#include <hip/hip_runtime.h>

// PermuteWeightSharing: out[row, s*16+k] = x[row, ppos[s]*16+k] - x[row, pneg[s]*16+k]
// row = (b,o,i) flattened, 256 floats per row = 16 slots x 16 floats.
//
// v2: grid-stride (2048 blocks, 16 iters/thread) so the per-block perm decode +
// __syncthreads amortizes 16x; stride is a multiple of 64 so the within-row
// geometry (v, slot, k4) is loop-invariant -> body is 2 loads at fixed deltas
// + 1 nontemporal store. Unroll 4 => 8 global_load_dwordx4 in flight (ILP).
// __launch_bounds__(256,8) keeps VGPR<=64 so all 524,288 threads are resident.

#define NSLOTS 16

typedef float fvec4 __attribute__((ext_vector_type(4)));

__global__ __launch_bounds__(256, 8) void permute_ws_kernel(
    const fvec4* __restrict__ x,
    const float* __restrict__ Ppos,
    const float* __restrict__ Pneg,
    fvec4* __restrict__ out,
    long total_v4)
{
    __shared__ int soff_p[NSLOTS];   // ppos[s] * 4  (float4 units)
    __shared__ int soff_n[NSLOTS];

    const int t = threadIdx.x;
    if (t < NSLOTS) {
        int ip = 0, in_ = 0;
        #pragma unroll
        for (int j = 0; j < NSLOTS; ++j) {
            if (Ppos[t * NSLOTS + j] > 0.5f) ip = j;
            if (Pneg[t * NSLOTS + j] > 0.5f) in_ = j;
        }
        soff_p[t] = ip << 2;
        soff_n[t] = in_ << 2;
    }
    __syncthreads();

    long idx = (long)blockIdx.x * blockDim.x + threadIdx.x;
    const long stride = (long)gridDim.x * (long)blockDim.x;   // multiple of 64

    // Within-row geometry is invariant across grid-stride steps (stride % 64 == 0).
    const int v    = (int)(idx & 63);   // float4 index within 256-float row
    const int slot = v >> 2;            // [0,16)
    const int k4   = v & 3;             // [0,4)
    // x index = row_base + soff + k4 = (idx - v) + soff + k4 = idx + delta
    const long dp = (long)(soff_p[slot] + k4 - v);
    const long dn = (long)(soff_n[slot] + k4 - v);

    long i = idx;
    // Main: 4-deep unrolled grid-stride. 8 loads in flight per thread.
    for (; i + 3 * stride < total_v4; i += 4 * stride) {
        const fvec4 a0 = x[i              + dp];
        const fvec4 b0 = x[i              + dn];
        const fvec4 a1 = x[i +     stride + dp];
        const fvec4 b1 = x[i +     stride + dn];
        const fvec4 a2 = x[i + 2 * stride + dp];
        const fvec4 b2 = x[i + 2 * stride + dn];
        const fvec4 a3 = x[i + 3 * stride + dp];
        const fvec4 b3 = x[i + 3 * stride + dn];
        const fvec4 r0 = a0 - b0;
        const fvec4 r1 = a1 - b1;
        const fvec4 r2 = a2 - b2;
        const fvec4 r3 = a3 - b3;
        // out is written once and never read: bypass caches, keep L2/L3 for x.
        __builtin_nontemporal_store(r0, &out[i]);
        __builtin_nontemporal_store(r1, &out[i +     stride]);
        __builtin_nontemporal_store(r2, &out[i + 2 * stride]);
        __builtin_nontemporal_store(r3, &out[i + 3 * stride]);
    }
    // Tail (not taken for the 8,388,608 / 524,288 = 16-iteration case).
    for (; i < total_v4; i += stride) {
        const fvec4 a = x[i + dp];
        const fvec4 b = x[i + dn];
        const fvec4 r = a - b;
        __builtin_nontemporal_store(r, &out[i]);
    }
}

extern "C" void kernel_launch(void* const* d_in, const int* in_sizes, int n_in,
                              void* d_out, int out_size, void* d_ws, size_t ws_size,
                              hipStream_t stream)
{
    const fvec4* x    = (const fvec4*)d_in[0];
    const float* Ppos = (const float*)d_in[1];
    const float* Pneg = (const float*)d_in[2];
    fvec4*       out  = (fvec4*)d_out;

    const long total_v4 = (long)out_size / 4;   // float4 count (33,554,432 / 4 = 8,388,608)

    const int block = 256;
    long blocks_needed = (total_v4 + block - 1) / block;
    // Cap at 2048 blocks (256 CU x 8 blocks/CU) and grid-stride the rest:
    // 16 iterations/thread amortizes the per-block perm decode + sync.
    int grid = (int)(blocks_needed > 2048 ? 2048 : blocks_needed);

    permute_ws_kernel<<<grid, block, 0, stream>>>(x, Ppos, Pneg, out, total_v4);
}